// Round 8
// baseline (35.714 us; speedup 1.0000x reference)
//
#include <hip/hip_runtime.h>
#include <hip/hip_bf16.h>

#define BATCH 16384
#define NCLS  1000
#define NPAD  1024
#define FDIM  512

// cbt layout per cblk: 8 slabs * 32KB ([chunk8][class256]x16B) + tail 4KB
#define CBLK_STRIDE 266240
#define TAIL_OFF    262144

typedef __bf16 bf16x4 __attribute__((ext_vector_type(4)));
typedef __bf16 bf16x8 __attribute__((ext_vector_type(8)));
typedef float  f32x16 __attribute__((ext_vector_type(16)));

#define GLOBAL_AS __attribute__((address_space(1)))
#define LDS_AS    __attribute__((address_space(3)))

#define VMCNT(n) asm volatile("s_waitcnt vmcnt(" #n ")" ::: "memory")
#define LGKM0()  asm volatile("s_waitcnt lgkmcnt(0)" ::: "memory")
#define SBAR()   __builtin_amdgcn_s_barrier()
#define SCHED0() __builtin_amdgcn_sched_barrier(0)

// ---------------------------------------------------------------------------
// prep: centers fp32 [1000][512] -> cbt pre-tiled BK=64 slab images; zeroes
// out[0] (combine atomicAdds into it on the same stream).
// ---------------------------------------------------------------------------
__global__ __launch_bounds__(64) void prep_centers(
    const float* __restrict__ centers, char* __restrict__ cbt,
    float* __restrict__ out)
{
    const int c = blockIdx.x, t = threadIdx.x;       // c 0..1023, t 0..63
    const int cblk = c >> 8, cl = c & 255;
    char* base = cbt + (size_t)cblk * CBLK_STRIDE;
    if (c == 0 && t == 0) out[0] = 0.f;

    float4 f0 = make_float4(0.f, 0.f, 0.f, 0.f);
    float4 f1 = make_float4(0.f, 0.f, 0.f, 0.f);
    if (c < NCLS) {
        f0 = *(const float4*)(centers + (size_t)c * FDIM + t * 8);
        f1 = *(const float4*)(centers + (size_t)c * FDIM + t * 8 + 4);
    }
    bf16x8 b;
    b[0] = (__bf16)f0.x; b[1] = (__bf16)f0.y; b[2] = (__bf16)f0.z; b[3] = (__bf16)f0.w;
    b[4] = (__bf16)f1.x; b[5] = (__bf16)f1.y; b[6] = (__bf16)f1.z; b[7] = (__bf16)f1.w;
    *(bf16x8*)(base + (t >> 3) * 32768 + (t & 7) * 4096 + cl * 16) = b;

    float ssum = f0.x*f0.x + f0.y*f0.y + f0.z*f0.z + f0.w*f0.w
               + f1.x*f1.x + f1.y*f1.y + f1.z*f1.z + f1.w*f1.w;
    #pragma unroll
    for (int o = 32; o > 0; o >>= 1) ssum += __shfl_down(ssum, o);
    if (t == 0) {
        const float hf = (c < NCLS) ? (-0.5f * ssum) : -1e30f;
        const __bf16 h = (__bf16)hf;
        const __bf16 l = (c < NCLS) ? (__bf16)(hf - (float)h) : (__bf16)0.f;
        bf16x8 tl;
        #pragma unroll
        for (int e = 0; e < 8; ++e) tl[e] = (__bf16)0.f;
        tl[0] = h; tl[1] = l;
        *(bf16x8*)(base + TAIL_OFF + cl * 16) = tl;
    }
}

// ---------------------------------------------------------------------------
// main: classes-as-M GEMM, acc[class][batch] = dot(c,x) - cn/2  (s = -2*acc)
//  block 256 cls x 256 batch, 8 waves (2M x 4N), wave 128x64 (4x2 frags).
//  grid = 256 -> 1/CU, 2 waves/SIMD; XCD = bid&7 = bblk&7.
//  BK=64, 8 slabs, double-buffered; *** 8-PHASE SCHEDULE (T3+T4+T5) ***:
//  each slab = 4 phases of {6 ds_read | 1/4 of next-slab VMEM issue |
//  s_barrier | lgkmcnt(0) | setprio(1) 8xMFMA setprio(0) | s_barrier}.
//  All vm-waits at P3: VMCNT(8) drains B(tt+1) (for writeB) AND A(tt+1)
//  (for next slab's pre-barrier ds_reads; visibility via P3 barrier pair).
//  LDS: A 2x32K @0 | B 2x32K @64K | tail 4K @128K
// ---------------------------------------------------------------------------
struct B8 { float4 a, b, c, d, e, f, g, h; };

__global__ __launch_bounds__(512, 1) void trip_main(
    const float* __restrict__ x, const int* __restrict__ labels,
    const char* __restrict__ cbt, float* __restrict__ mxp,
    float* __restrict__ dap)
{
    extern __shared__ char lds[];
    const int t    = threadIdx.x;
    const int lane = t & 63;
    const int w    = t >> 6;          // 0..7
    const int wN   = w & 3, wM = w >> 2;
    const int l31  = lane & 31, hi = lane >> 5;
    const int bid  = blockIdx.x;
    const int cblk = bid >> 6;        // 0..3
    const int bblk = bid & 63;        // 0..63 -> XCD = bblk & 7
    const int class0 = cblk * 256;
    const int row0   = bblk * 256;
    const char* cbB  = cbt + (size_t)cblk * CBLK_STRIDE;

    auto stageA = [&](int ko, int ai) {   // 32KB contiguous memcpy, 4 DMA
        const char* src = cbB + ko * 32768 + t * 16;
        char* dst = lds + ai * 32768 + t * 16;
        #pragma unroll
        for (int j = 0; j < 4; ++j)
            __builtin_amdgcn_global_load_lds(
                (const GLOBAL_AS void*)(src + j * 8192),
                (LDS_AS void*)(dst + j * 8192), 16, 0, 0);
    };
    auto loadB_lo = [&](int ko, B8& br) { // 4 dwordx4, rows +0/+8
        const float* src = x + (size_t)(row0 + w * 32 + (lane >> 3)) * FDIM
                         + ko * 64 + (lane & 7) * 4;
        br.a = *(const float4*)(src);
        br.b = *(const float4*)(src + 32);
        br.c = *(const float4*)(src +  8 * FDIM);
        br.d = *(const float4*)(src +  8 * FDIM + 32);
    };
    auto loadB_hi = [&](int ko, B8& br) { // 4 dwordx4, rows +16/+24
        const float* src = x + (size_t)(row0 + w * 32 + (lane >> 3)) * FDIM
                         + ko * 64 + (lane & 7) * 4;
        br.e = *(const float4*)(src + 16 * FDIM);
        br.f = *(const float4*)(src + 16 * FDIM + 32);
        br.g = *(const float4*)(src + 24 * FDIM);
        br.h = *(const float4*)(src + 24 * FDIM + 32);
    };
    auto cv4 = [](float4 f) {
        bf16x4 v;
        v[0] = (__bf16)f.x; v[1] = (__bf16)f.y;
        v[2] = (__bf16)f.z; v[3] = (__bf16)f.w;
        return v;
    };
    auto writeB = [&](const B8& br, int bi) {   // 8 ds_write_b64
        char* dst = lds + 65536 + bi * 32768 + ((lane & 7) >> 1) * 4096
                  + (w * 32 + (lane >> 3)) * 16 + (lane & 1) * 8;
        *(bf16x4*)(dst                 ) = cv4(br.a);
        *(bf16x4*)(dst + 4 * 4096      ) = cv4(br.b);
        *(bf16x4*)(dst + 128           ) = cv4(br.c);
        *(bf16x4*)(dst + 4 * 4096 + 128) = cv4(br.d);
        *(bf16x4*)(dst + 256           ) = cv4(br.e);
        *(bf16x4*)(dst + 4 * 4096 + 256) = cv4(br.f);
        *(bf16x4*)(dst + 384           ) = cv4(br.g);
        *(bf16x4*)(dst + 4 * 4096 + 384) = cv4(br.h);
    };

    f32x16 acc[4][2];
    #pragma unroll
    for (int mi = 0; mi < 4; ++mi)
        #pragma unroll
        for (int ni = 0; ni < 2; ++ni)
            #pragma unroll
            for (int r = 0; r < 16; ++r) acc[mi][ni][r] = 0.f;

    // ---- prologue (ledger: lab 2, tail 1, A0 4, B0 8 | B1 8) ----
    const int lab0 = labels[row0 + wN * 64 + l31];
    const int lab1 = labels[row0 + wN * 64 + 32 + l31];
    if (t < 256) {   // tail A: 4KB contiguous memcpy (waves 0-3 only)
        const char* src = cbB + TAIL_OFF + t * 16;
        char* dst = lds + 131072 + t * 16;
        __builtin_amdgcn_global_load_lds((const GLOBAL_AS void*)src,
                                         (LDS_AS void*)dst, 16, 0, 0);
    }
    B8 brA, brB;
    stageA(0, 0);
    loadB_lo(0, brA); loadB_hi(0, brA);
    SCHED0();                       // pin: {lab,tail,A0,B0} before B1
    loadB_lo(1, brB); loadB_hi(1, brB);
    VMCNT(8);                       // drain lab+tail+A0+B0; keep B1(8)
    writeB(brA, 0);
    LGKM0(); SBAR(); SCHED0();      // B0/A0 visible to all waves

    // ---- K pipeline: 8 slabs x 4 phases, FULLY UNROLLED ----
    #pragma unroll
    for (int tt = 0; tt < 8; ++tt) {
        const int cur = tt & 1, oth = cur ^ 1;
        const char* A  = lds + cur * 32768;
        const char* Bb = lds + 65536 + cur * 32768;
        #pragma unroll
        for (int p = 0; p < 4; ++p) {
            // ---- pre-section: vm-wait (P3 only), ds_read, VMEM issue ----
            if (p == 3) {
                if (tt <= 5)      VMCNT(8);   // drain B(tt+1)+A(tt+1), keep B(tt+2)
                else if (tt == 6) VMCNT(0);   // drain B7+A7 (no B8 exists)
            }
            const int chunk = p * 2 + hi;
            bf16x8 a0 = *(const bf16x8*)(A + chunk * 4096 + (wM * 128 +  0 + l31) * 16);
            bf16x8 a1 = *(const bf16x8*)(A + chunk * 4096 + (wM * 128 + 32 + l31) * 16);
            bf16x8 a2 = *(const bf16x8*)(A + chunk * 4096 + (wM * 128 + 64 + l31) * 16);
            bf16x8 a3 = *(const bf16x8*)(A + chunk * 4096 + (wM * 128 + 96 + l31) * 16);
            bf16x8 b0 = *(const bf16x8*)(Bb + chunk * 4096 + (wN * 64 +  0 + l31) * 16);
            bf16x8 b1 = *(const bf16x8*)(Bb + chunk * 4096 + (wN * 64 + 32 + l31) * 16);
            if (p == 0 && tt < 7) stageA(tt + 1, oth);
            if (p == 1 && tt <= 5) {
                if (tt & 1) loadB_lo(tt + 2, brB);
                else        loadB_lo(tt + 2, brA);
            }
            if (p == 2 && tt <= 5) {
                if (tt & 1) loadB_hi(tt + 2, brB);
                else        loadB_hi(tt + 2, brA);
            }
            if (p == 3 && tt <= 6) {
                if (tt & 1) writeB(brA, oth);
                else        writeB(brB, oth);
            }
            // ---- MFMA cluster ----
            SBAR();
            LGKM0();
            SCHED0();
            __builtin_amdgcn_s_setprio(1);
            acc[0][0] = __builtin_amdgcn_mfma_f32_32x32x16_bf16(a0, b0, acc[0][0], 0, 0, 0);
            acc[0][1] = __builtin_amdgcn_mfma_f32_32x32x16_bf16(a0, b1, acc[0][1], 0, 0, 0);
            acc[1][0] = __builtin_amdgcn_mfma_f32_32x32x16_bf16(a1, b0, acc[1][0], 0, 0, 0);
            acc[1][1] = __builtin_amdgcn_mfma_f32_32x32x16_bf16(a1, b1, acc[1][1], 0, 0, 0);
            acc[2][0] = __builtin_amdgcn_mfma_f32_32x32x16_bf16(a2, b0, acc[2][0], 0, 0, 0);
            acc[2][1] = __builtin_amdgcn_mfma_f32_32x32x16_bf16(a2, b1, acc[2][1], 0, 0, 0);
            acc[3][0] = __builtin_amdgcn_mfma_f32_32x32x16_bf16(a3, b0, acc[3][0], 0, 0, 0);
            acc[3][1] = __builtin_amdgcn_mfma_f32_32x32x16_bf16(a3, b1, acc[3][1], 0, 0, 0);
            __builtin_amdgcn_s_setprio(0);
            SBAR();
            SCHED0();
        }
    }

    // ---- tail k-step (k 512..527): A from tail LDS, B = (1,1,0,...) ----
    {
        const char* T = lds + 131072;
        bf16x8 bt;
        #pragma unroll
        for (int e = 0; e < 8; ++e) bt[e] = (__bf16)0.f;
        if (hi == 0) { bt[0] = (__bf16)1.0f; bt[1] = (__bf16)1.0f; }
        #pragma unroll
        for (int mi = 0; mi < 4; ++mi) {
            bf16x8 a = *(const bf16x8*)(T + (wM * 128 + mi * 32 + l31) * 16);
            #pragma unroll
            for (int ni = 0; ni < 2; ++ni)
                acc[mi][ni] = __builtin_amdgcn_mfma_f32_32x32x16_bf16(
                    a, bt, acc[mi][ni], 0, 0, 0);
        }
    }

    // ---- epilogue: per-lane max over non-label classes + label acc ----
    const int labBase = class0 + wM * 128 + hi * 4;
    const int labA0 = lab0 - labBase;
    const int labA1 = lab1 - labBase;
    float MX0 = -3e38f, MX1 = -3e38f, DA0 = -3e38f, DA1 = -3e38f;
    #pragma unroll
    for (int mi = 0; mi < 4; ++mi) {
        #pragma unroll
        for (int r = 0; r < 16; ++r) {
            const int pat = mi * 32 + (r & 3) + 8 * (r >> 2);
            {
                const float a = acc[mi][0][r];
                const bool is = (labA0 == pat);
                MX0 = fmaxf(MX0, is ? -3e38f : a);
                DA0 = is ? a : DA0;
            }
            {
                const float a = acc[mi][1][r];
                const bool is = (labA1 == pat);
                MX1 = fmaxf(MX1, is ? -3e38f : a);
                DA1 = is ? a : DA1;
            }
        }
    }
    MX0 = fmaxf(MX0, __shfl_xor(MX0, 32));
    DA0 = fmaxf(DA0, __shfl_xor(DA0, 32));
    MX1 = fmaxf(MX1, __shfl_xor(MX1, 32));
    DA1 = fmaxf(DA1, __shfl_xor(DA1, 32));

    // ---- merge the two M-waves via scratch (B buf0, retired), store ----
    float* sc = (float*)(lds + 65536);    // [256] MX, [256] DA
    const int i0 = (wN * 2 + 0) * 32 + l31;
    const int i1 = (wN * 2 + 1) * 32 + l31;
    if (wM == 1 && hi == 0) {
        sc[i0] = MX0; sc[256 + i0] = DA0;
        sc[i1] = MX1; sc[256 + i1] = DA1;
    }
    __syncthreads();
    if (wM == 0 && hi == 0) {
        const float M0 = fmaxf(MX0, sc[i0]),  D0 = fmaxf(DA0, sc[256 + i0]);
        const float M1 = fmaxf(MX1, sc[i1]),  D1 = fmaxf(DA1, sc[256 + i1]);
        const int rg = row0 + wN * 64 + l31;
        mxp[cblk * BATCH + rg]      = M0;
        dap[cblk * BATCH + rg]      = D0;
        mxp[cblk * BATCH + rg + 32] = M1;
        dap[cblk * BATCH + rg + 32] = D1;
    }
}

// ---------------------------------------------------------------------------
// combine: fold 4 cblk partials, hinge, block-sum, one atomicAdd per block.
// out[0] zeroed by prep_centers (stream-ordered before this kernel).
// ---------------------------------------------------------------------------
__global__ __launch_bounds__(256) void combine(
    const float* __restrict__ mxp, const float* __restrict__ dap,
    const float* __restrict__ margin, float* __restrict__ out)
{
    const int t = threadIdx.x;
    const int row = blockIdx.x * 256 + t;
    float mx = fmaxf(fmaxf(mxp[row], mxp[BATCH + row]),
                     fmaxf(mxp[2 * BATCH + row], mxp[3 * BATCH + row]));
    float da = fmaxf(fmaxf(dap[row], dap[BATCH + row]),
                     fmaxf(dap[2 * BATCH + row], dap[3 * BATCH + row]));
    // dist = -2*da, dist_min = -2*mx
    float loss = fmaxf(margin[0] - 2.f * da + 2.f * mx, 0.f);
    __shared__ float red[4];
    #pragma unroll
    for (int o = 32; o > 0; o >>= 1) loss += __shfl_down(loss, o);
    if ((t & 63) == 0) red[t >> 6] = loss;
    __syncthreads();
    if (t == 0)
        atomicAdd(out, (red[0] + red[1] + red[2] + red[3]) * (1.0f / BATCH));
}

// ---------------------------------------------------------------------------
extern "C" void kernel_launch(void* const* d_in, const int* in_sizes, int n_in,
                              void* d_out, int out_size, void* d_ws, size_t ws_size,
                              hipStream_t stream)
{
    const float* x       = (const float*)d_in[0];
    const int*   labels  = (const int*)d_in[1];
    const float* centers = (const float*)d_in[2];
    const float* margin  = (const float*)d_in[3];
    float* out = (float*)d_out;

    char* ws = (char*)d_ws;
    char*  cbt  = ws;                                  // 1,064,960 B
    float* mxp  = (float*)(ws + 1064960);              //   262,144 B
    float* dap  = (float*)(ws + 1327104);              //   262,144 B

    (void)hipFuncSetAttribute((const void*)trip_main,
                              hipFuncAttributeMaxDynamicSharedMemorySize, 135168);

    prep_centers<<<NPAD, 64, 0, stream>>>(centers, cbt, out);
    trip_main<<<256, 512, 135168, stream>>>(x, labels, cbt, mxp, dap);
    combine<<<64, 256, 0, stream>>>(mxp, dap, margin, out);
}

// Round 9
// 32.967 us; speedup vs baseline: 1.0833x; 1.0833x over previous
//
#include <hip/hip_runtime.h>
#include <hip/hip_bf16.h>

#define BATCH 16384
#define NCLS  1000
#define NPAD  1024
#define FDIM  512

// cbt layout per cblk: 16 slabs * 16KB ([chunk4][class256]x16B) + tail 4KB
#define CBLK_STRIDE 266240
#define TAIL_OFF    262144

typedef __bf16 bf16x4 __attribute__((ext_vector_type(4)));
typedef __bf16 bf16x8 __attribute__((ext_vector_type(8)));
typedef float  f32x16 __attribute__((ext_vector_type(16)));

#define GLOBAL_AS __attribute__((address_space(1)))
#define LDS_AS    __attribute__((address_space(3)))

#define VMCNT(n) asm volatile("s_waitcnt vmcnt(" #n ")" ::: "memory")
#define LGKM0()  asm volatile("s_waitcnt lgkmcnt(0)" ::: "memory")
#define BAR()    do { LGKM0(); __builtin_amdgcn_s_barrier(); \
                      __builtin_amdgcn_sched_barrier(0); } while (0)

// ---------------------------------------------------------------------------
// prep: centers fp32 [1000][512] -> cbt pre-tiled BK=32 slab images; zeroes
// out[0] (combine atomicAdds into it on the same stream).
// thread t owns floats t*8..t*8+8: slab t>>2, chunk t&3.
// ---------------------------------------------------------------------------
__global__ __launch_bounds__(64) void prep_centers(
    const float* __restrict__ centers, char* __restrict__ cbt,
    float* __restrict__ out)
{
    const int c = blockIdx.x, t = threadIdx.x;       // c 0..1023, t 0..63
    const int cblk = c >> 8, cl = c & 255;
    char* base = cbt + (size_t)cblk * CBLK_STRIDE;
    if (c == 0 && t == 0) out[0] = 0.f;

    float4 f0 = make_float4(0.f, 0.f, 0.f, 0.f);
    float4 f1 = make_float4(0.f, 0.f, 0.f, 0.f);
    if (c < NCLS) {
        f0 = *(const float4*)(centers + (size_t)c * FDIM + t * 8);
        f1 = *(const float4*)(centers + (size_t)c * FDIM + t * 8 + 4);
    }
    bf16x8 b;
    b[0] = (__bf16)f0.x; b[1] = (__bf16)f0.y; b[2] = (__bf16)f0.z; b[3] = (__bf16)f0.w;
    b[4] = (__bf16)f1.x; b[5] = (__bf16)f1.y; b[6] = (__bf16)f1.z; b[7] = (__bf16)f1.w;
    *(bf16x8*)(base + (t >> 2) * 16384 + (t & 3) * 4096 + cl * 16) = b;

    float ssum = f0.x*f0.x + f0.y*f0.y + f0.z*f0.z + f0.w*f0.w
               + f1.x*f1.x + f1.y*f1.y + f1.z*f1.z + f1.w*f1.w;
    #pragma unroll
    for (int o = 32; o > 0; o >>= 1) ssum += __shfl_down(ssum, o);
    if (t == 0) {
        const float hf = (c < NCLS) ? (-0.5f * ssum) : -1e30f;
        const __bf16 h = (__bf16)hf;
        const __bf16 l = (c < NCLS) ? (__bf16)(hf - (float)h) : (__bf16)0.f;
        bf16x8 tl;
        #pragma unroll
        for (int e = 0; e < 8; ++e) tl[e] = (__bf16)0.f;
        tl[0] = h; tl[1] = l;
        *(bf16x8*)(base + TAIL_OFF + cl * 16) = tl;
    }
}

// ---------------------------------------------------------------------------
// main: classes-as-M GEMM, acc[class][batch] = dot(c,x) - cn/2  (s = -2*acc)
//  *** OCCUPANCY ROUND: 16 waves/CU (4/SIMD), 2 blocks/CU ***
//  block 256 cls x 128 batch, 8 waves (4M x 2N), wave 64x64 (2x2 frags).
//  grid = 4 cblk * 128 bblk = 512 blocks, LDS 52KB -> 2 blocks/CU.
//  __launch_bounds__(512,4) caps VGPR at 128 (acc is only 64 now).
//  BK=32, 16 slabs, double-buffered, SOUND ledger: per iter issue A(tt+1)[2]
//  + B(tt+2)[2], VMCNT(2) drains A(tt+1)+B(tt+1) BEFORE the barrier, so all
//  waves' staging is complete at the barrier every reader crosses.
//  LDS: A 2x16K @0 | B 2x8K @32K | tail 4K @48K
// ---------------------------------------------------------------------------
struct B2 { float4 a, b; };

__global__ __launch_bounds__(512, 4) void trip_main(
    const float* __restrict__ x, const int* __restrict__ labels,
    const char* __restrict__ cbt, float* __restrict__ mxp,
    float* __restrict__ dap)
{
    extern __shared__ char lds[];
    const int t    = threadIdx.x;
    const int lane = t & 63;
    const int w    = t >> 6;          // 0..7
    const int wM   = w >> 1, wN = w & 1;
    const int l31  = lane & 31, hi = lane >> 5;
    const int bid  = blockIdx.x;
    const int cblk = bid >> 7;        // 0..3
    const int bblk = bid & 127;       // 0..127 -> XCD = bblk & 7
    const int class0 = cblk * 256;
    const int row0   = bblk * 128;
    const char* cbB  = cbt + (size_t)cblk * CBLK_STRIDE;

    auto stageA = [&](int ko, int ai) {   // 16KB contiguous memcpy, 2 instr
        const char* src = cbB + ko * 16384 + t * 16;
        char* dst = lds + ai * 16384 + t * 16;
        __builtin_amdgcn_global_load_lds((const GLOBAL_AS void*)src,
                                         (LDS_AS void*)dst, 16, 0, 0);
        __builtin_amdgcn_global_load_lds((const GLOBAL_AS void*)(src + 8192),
                                         (LDS_AS void*)(dst + 8192), 16, 0, 0);
    };
    auto loadB = [&](int ko, B2& br) {    // 2 dwordx4, 8 full lines each
        const float* src = x + (size_t)(row0 + w * 16 + (lane >> 3)) * FDIM
                         + ko * 32 + (lane & 7) * 4;
        br.a = *(const float4*)(src);
        br.b = *(const float4*)(src + 8 * FDIM);
    };
    auto cv4 = [](float4 f) {
        bf16x4 v;
        v[0] = (__bf16)f.x; v[1] = (__bf16)f.y;
        v[2] = (__bf16)f.z; v[3] = (__bf16)f.w;
        return v;
    };
    auto writeB = [&](const B2& br, int bi) {   // 2 ds_write_b64
        char* dst = lds + 32768 + bi * 8192 + ((lane & 7) >> 1) * 2048
                  + (w * 16 + (lane >> 3)) * 16 + (lane & 1) * 8;
        *(bf16x4*)(dst      ) = cv4(br.a);
        *(bf16x4*)(dst + 128) = cv4(br.b);       // row +8
    };

    f32x16 acc[2][2];
    #pragma unroll
    for (int mi = 0; mi < 2; ++mi)
        #pragma unroll
        for (int ni = 0; ni < 2; ++ni)
            #pragma unroll
            for (int r = 0; r < 16; ++r) acc[mi][ni][r] = 0.f;

    auto compute = [&](int buf) {
        const char* A = lds + buf * 16384;
        const char* B = lds + 32768 + buf * 8192;
        #pragma unroll
        for (int ks = 0; ks < 2; ++ks) {
            const int chunk = ks * 2 + hi;
            bf16x8 a0 = *(const bf16x8*)(A + chunk * 4096 + (wM * 64 +  0 + l31) * 16);
            bf16x8 a1 = *(const bf16x8*)(A + chunk * 4096 + (wM * 64 + 32 + l31) * 16);
            bf16x8 b0 = *(const bf16x8*)(B + chunk * 2048 + (wN * 64 +  0 + l31) * 16);
            bf16x8 b1 = *(const bf16x8*)(B + chunk * 2048 + (wN * 64 + 32 + l31) * 16);
            acc[0][0] = __builtin_amdgcn_mfma_f32_32x32x16_bf16(a0, b0, acc[0][0], 0, 0, 0);
            acc[0][1] = __builtin_amdgcn_mfma_f32_32x32x16_bf16(a0, b1, acc[0][1], 0, 0, 0);
            acc[1][0] = __builtin_amdgcn_mfma_f32_32x32x16_bf16(a1, b0, acc[1][0], 0, 0, 0);
            acc[1][1] = __builtin_amdgcn_mfma_f32_32x32x16_bf16(a1, b1, acc[1][1], 0, 0, 0);
        }
    };

    // ---- prologue (ledger: lab 2, tail <=1, A0 2, B0 2 | B1 2) ----
    const int lab0 = labels[row0 + wN * 64 + l31];
    const int lab1 = labels[row0 + wN * 64 + 32 + l31];
    if (t < 256) {   // tail A: 4KB contiguous memcpy
        const char* src = cbB + TAIL_OFF + t * 16;
        char* dst = lds + 49152 + t * 16;
        __builtin_amdgcn_global_load_lds((const GLOBAL_AS void*)src,
                                         (LDS_AS void*)dst, 16, 0, 0);
    }
    B2 brA, brB;
    stageA(0, 0); loadB(0, brA);
    __builtin_amdgcn_sched_barrier(0);   // pin: {lab,tail,A0,B0} before B1
    loadB(1, brB);
    VMCNT(2);                            // drain lab+tail+A0+B0; keep B1
    writeB(brA, 0);
    BAR();

    // ---- K pipeline: 16 slabs of 32, FULLY UNROLLED, sound drains ----
    #pragma unroll
    for (int tt = 0; tt < 16; ++tt) {
        const int cur = tt & 1, oth = cur ^ 1;
        if (tt < 15) stageA(tt + 1, oth);
        if (tt <= 13) {
            if (tt & 1) loadB(tt + 2, brB);
            else        loadB(tt + 2, brA);
        }
        if (tt <= 13)      VMCNT(2);   // drain A(tt+1)+B(tt+1); keep B(tt+2)
        else if (tt == 14) VMCNT(0);   // drain A(15)+B(15)
        if (tt <= 14) {
            if (tt & 1) writeB(brA, oth);
            else        writeB(brB, oth);
        }
        compute(cur);
        BAR();                         // staging for tt+1 complete in ALL waves
    }

    // ---- tail k-step (k 512..527): A from tail LDS, B = (1,1,0,...) ----
    {
        const char* T = lds + 49152;
        bf16x8 bt;
        #pragma unroll
        for (int e = 0; e < 8; ++e) bt[e] = (__bf16)0.f;
        if (hi == 0) { bt[0] = (__bf16)1.0f; bt[1] = (__bf16)1.0f; }
        #pragma unroll
        for (int mi = 0; mi < 2; ++mi) {
            bf16x8 a = *(const bf16x8*)(T + (wM * 64 + mi * 32 + l31) * 16);
            #pragma unroll
            for (int ni = 0; ni < 2; ++ni)
                acc[mi][ni] = __builtin_amdgcn_mfma_f32_32x32x16_bf16(
                    a, bt, acc[mi][ni], 0, 0, 0);
        }
    }

    // ---- epilogue: per-lane max over non-label classes + label acc ----
    const int labBase = class0 + wM * 64 + hi * 4;
    const int labA0 = lab0 - labBase;
    const int labA1 = lab1 - labBase;
    float MX0 = -3e38f, MX1 = -3e38f, DA0 = -3e38f, DA1 = -3e38f;
    #pragma unroll
    for (int mi = 0; mi < 2; ++mi) {
        #pragma unroll
        for (int r = 0; r < 16; ++r) {
            const int pat = mi * 32 + (r & 3) + 8 * (r >> 2);
            {
                const float a = acc[mi][0][r];
                const bool is = (labA0 == pat);
                MX0 = fmaxf(MX0, is ? -3e38f : a);
                DA0 = is ? a : DA0;
            }
            {
                const float a = acc[mi][1][r];
                const bool is = (labA1 == pat);
                MX1 = fmaxf(MX1, is ? -3e38f : a);
                DA1 = is ? a : DA1;
            }
        }
    }
    MX0 = fmaxf(MX0, __shfl_xor(MX0, 32));
    DA0 = fmaxf(DA0, __shfl_xor(DA0, 32));
    MX1 = fmaxf(MX1, __shfl_xor(MX1, 32));
    DA1 = fmaxf(DA1, __shfl_xor(DA1, 32));

    // ---- merge 4 M-wave planes via scratch (A buf0, retired) ----
    float* scm = (float*)lds;             // [512] MX planes
    float* scd = scm + 512;               // [512] DA planes
    __syncthreads();                      // everyone past compute; A buf0 free
    if (hi == 0) {
        const int r0 = wN * 64 + l31;
        scm[wM * 128 + r0]      = MX0;  scd[wM * 128 + r0]      = DA0;
        scm[wM * 128 + r0 + 32] = MX1;  scd[wM * 128 + r0 + 32] = DA1;
    }
    __syncthreads();
    if (t < 128) {
        const float mx = fmaxf(fmaxf(scm[t], scm[128 + t]),
                               fmaxf(scm[256 + t], scm[384 + t]));
        const float da = fmaxf(fmaxf(scd[t], scd[128 + t]),
                               fmaxf(scd[256 + t], scd[384 + t]));
        mxp[cblk * BATCH + row0 + t] = mx;
        dap[cblk * BATCH + row0 + t] = da;
    }
}

// ---------------------------------------------------------------------------
// combine: fold 4 cblk partials, hinge, block-sum, one atomicAdd per block.
// out[0] zeroed by prep_centers (stream-ordered before this kernel).
// ---------------------------------------------------------------------------
__global__ __launch_bounds__(256) void combine(
    const float* __restrict__ mxp, const float* __restrict__ dap,
    const float* __restrict__ margin, float* __restrict__ out)
{
    const int t = threadIdx.x;
    const int row = blockIdx.x * 256 + t;
    float mx = fmaxf(fmaxf(mxp[row], mxp[BATCH + row]),
                     fmaxf(mxp[2 * BATCH + row], mxp[3 * BATCH + row]));
    float da = fmaxf(fmaxf(dap[row], dap[BATCH + row]),
                     fmaxf(dap[2 * BATCH + row], dap[3 * BATCH + row]));
    // dist = -2*da, dist_min = -2*mx
    float loss = fmaxf(margin[0] - 2.f * da + 2.f * mx, 0.f);
    __shared__ float red[4];
    #pragma unroll
    for (int o = 32; o > 0; o >>= 1) loss += __shfl_down(loss, o);
    if ((t & 63) == 0) red[t >> 6] = loss;
    __syncthreads();
    if (t == 0)
        atomicAdd(out, (red[0] + red[1] + red[2] + red[3]) * (1.0f / BATCH));
}

// ---------------------------------------------------------------------------
extern "C" void kernel_launch(void* const* d_in, const int* in_sizes, int n_in,
                              void* d_out, int out_size, void* d_ws, size_t ws_size,
                              hipStream_t stream)
{
    const float* x       = (const float*)d_in[0];
    const int*   labels  = (const int*)d_in[1];
    const float* centers = (const float*)d_in[2];
    const float* margin  = (const float*)d_in[3];
    float* out = (float*)d_out;

    char* ws = (char*)d_ws;
    char*  cbt  = ws;                                  // 1,064,960 B
    float* mxp  = (float*)(ws + 1064960);              //   262,144 B
    float* dap  = (float*)(ws + 1327104);              //   262,144 B

    (void)hipFuncSetAttribute((const void*)trip_main,
                              hipFuncAttributeMaxDynamicSharedMemorySize, 53248);

    prep_centers<<<NPAD, 64, 0, stream>>>(centers, cbt, out);
    trip_main<<<512, 512, 53248, stream>>>(x, labels, cbt, mxp, dap);
    combine<<<64, 256, 0, stream>>>(mxp, dap, margin, out);
}